// Round 11
// baseline (1099.761 us; speedup 1.0000x reference)
//
#include <hip/hip_runtime.h>
#include <hip/hip_bf16.h>
#include <hip/hip_fp16.h>
#include <stdint.h>

#define M_DIM 4096   // B*S
#define K_DIM 2048   // H
#define N_DIM 8192   // OUT

typedef __attribute__((ext_vector_type(4))) float f32x4;
typedef __attribute__((ext_vector_type(8))) _Float16 f16x8;

typedef __attribute__((address_space(1))) const unsigned int g_u32_t;
typedef __attribute__((address_space(3))) unsigned int lds_u32_t;

static __device__ __forceinline__ void gload16(const void* g, void* l) {
  // global -> LDS direct copy, 16B per lane; LDS dest = wave-uniform base + lane*16
  __builtin_amdgcn_global_load_lds((g_u32_t*)g, (lds_u32_t*)l, 16, 0, 0);
}

#define BOUNDF ((float)(-2.053748910631823))

__device__ __forceinline__ unsigned char gate_passed(float y1v, float sqv,
                                                     float sw, float sb) {
  // mirrors the reference op-for-op; cm*cm is PINNED so the compiler cannot
  // contract (sqv/32 - cm*cm) into fma(-cm, cm, sqv/32) — knife-edge gate
  // elements flip on that 1-ulp difference (round-8/9 failure mode).
  float cm = y1v / 32.0f * sw + sb;
  float cmsq = cm * cm;
  asm volatile("" : "+v"(cmsq));
  float cv = (sqv / 32.0f - cmsq) * sw * sw;
  float ts = cm / sqrtf(cv / 32.0f);
  return (ts < BOUNDF) ? (unsigned char)1 : (unsigned char)0;
}

// ------- fused convert fp32 -> fp16 (RTN) for BOTH x and w, plus packed E-prefix -------
__global__ void cvt_f16_fused_kernel(const float* __restrict__ x,
                                     const float* __restrict__ wgt,
                                     unsigned short* __restrict__ xf,
                                     unsigned short* __restrict__ wf,
                                     float* __restrict__ xe,
                                     float* __restrict__ we,
                                     int n4x, int n4tot) {
  int i = blockIdx.x * blockDim.x + threadIdx.x;
  int stride = gridDim.x * blockDim.x;
  for (; i < n4tot; i += stride) {
    const float* src;
    unsigned short* dst;
    float* pe;
    int idx;
    if (i < n4x) {
      src = x; dst = xf; pe = xe; idx = i;
    } else {
      src = wgt; dst = wf; pe = we; idx = i - n4x;
    }
    float4 v = reinterpret_cast<const float4*>(src)[idx];
    int col4 = idx & (K_DIM / 4 - 1);
    if (col4 < 8) {
      int row = idx >> 9;  // K_DIM/4 = 512
      reinterpret_cast<float4*>(pe)[row * 8 + col4] = v;
    }
    float xs[4] = {v.x, v.y, v.z, v.w};
    unsigned short hb[4];
#pragma unroll
    for (int j = 0; j < 4; ++j) {
      _Float16 h = (_Float16)xs[j];  // v_cvt_f16_f32, round-to-nearest
      hb[j] = *reinterpret_cast<unsigned short*>(&h);
    }
    reinterpret_cast<ushort4*>(dst)[idx] = make_ushort4(hb[0], hb[1], hb[2], hb[3]);
  }
}

// ---------------- gate mask kernel: exact fp32 E=32 stats -> byte mask ----------------
// k-OUTER restructure (round-11): all 16 rows' accumulators live (y1/sq[16][4],
// 128 VGPRs — affordable here because there is no GEMM acc in this kernel), so
// wv is read ONCE per k instead of once per m: LDS reads 1024 -> 640 per thread.
// Per-output fmaf chain is bit-identical to rounds 3-10 (k ascends for every
// output; all acc indices compile-time per rule #20).
// LDS access patterns unchanged from the proven round-6/10 code (0 conflicts).
__global__ void mask_kernel(
    const float* __restrict__ xe_packed, const float* __restrict__ we_packed,
    const float* __restrict__ bias, const float* __restrict__ swp,
    const float* __restrict__ sbp, unsigned char* __restrict__ mask) {
  __shared__ __align__(16) unsigned char smem_bytes[128 * 36 * 4 + 32 * 128 * 4];
  float* xe_lds = (float*)smem_bytes;                      // [128][36]
  float* we_lds = (float*)(smem_bytes + 128 * 36 * 4);     // [32][128]

  int row0 = blockIdx.x * 128, col0 = blockIdx.y * 128;
  int t = threadIdx.x, lane = t & 63, w = t >> 6;
  int wrow = (w >> 1) * 64, wcol = (w & 1) * 64;
  int cl = lane & 15, rg = lane >> 4;

  // stage x_e tile: 128 rows x 32 f32 = 1024 float4; 4 per thread
#pragma unroll
  for (int it = 0; it < 4; ++it) {
    int idx = it * 256 + t;
    int r = idx >> 3, q = idx & 7;
    float4 v = reinterpret_cast<const float4*>(xe_packed)[(size_t)(row0 + r) * 8 + q];
    *reinterpret_cast<float4*>(&xe_lds[r * 36 + q * 4]) = v;
  }
  // stage w_e tile transposed to k-major: [32][128]
#pragma unroll
  for (int it = 0; it < 4; ++it) {
    int idx = it * 256 + t;
    int c = idx & 127, kq = idx >> 7;  // kq = 0..7
    float4 v = reinterpret_cast<const float4*>(we_packed)[(size_t)(col0 + c) * 8 + kq];
    we_lds[(kq * 4 + 0) * 128 + c] = v.x;
    we_lds[(kq * 4 + 1) * 128 + c] = v.y;
    we_lds[(kq * 4 + 2) * 128 + c] = v.z;
    we_lds[(kq * 4 + 3) * 128 + c] = v.w;
  }
  __syncthreads();

  float sw = *swp, sb = *sbp;

  float y1[16][4], sq[16][4];  // [m*4+j][n]
#pragma unroll
  for (int r = 0; r < 16; ++r)
#pragma unroll
    for (int n = 0; n < 4; ++n) { y1[r][n] = 0.0f; sq[r][n] = 0.0f; }

#pragma unroll 2
  for (int k = 0; k < 32; ++k) {
    float wv[4], wv2[4];
#pragma unroll
    for (int n = 0; n < 4; ++n) {
      wv[n] = we_lds[k * 128 + wcol + n * 16 + cl];
      wv2[n] = wv[n] * wv[n];
    }
#pragma unroll
    for (int m = 0; m < 4; ++m) {
#pragma unroll
      for (int j = 0; j < 4; ++j) {
        float xv = xe_lds[(wrow + m * 16 + rg * 4 + j) * 36 + k];
        float xv2 = xv * xv;
#pragma unroll
        for (int n = 0; n < 4; ++n) {
          y1[m * 4 + j][n] = fmaf(xv, wv[n], y1[m * 4 + j][n]);
          sq[m * 4 + j][n] = fmaf(xv2, wv2[n], sq[m * 4 + j][n]);
        }
      }
    }
  }

#pragma unroll
  for (int m = 0; m < 4; ++m) {
#pragma unroll
    for (int n = 0; n < 4; ++n) {
      int c = col0 + wcol + n * 16 + cl;
      float bv = bias[c];
#pragma unroll
      for (int j = 0; j < 4; ++j) {
        int r = row0 + wrow + m * 16 + rg * 4 + j;
        mask[(size_t)r * N_DIM + c] =
            gate_passed(y1[m * 4 + j][n] + bv, sq[m * 4 + j][n], sw, sb);
      }
    }
  }
}

// ---------------- main GEMM: single fp16 MFMA term, mask-select epilogue ----------------
// m97 structure: 128x128 tile, BK=32, 4 waves, global_load_lds width 16,
// XOR-swizzled 16B LDS slots, 8 ds_read_b128 + 16 MFMA per K-step.
// LDS = 16 KB only (gate moved out) -> high residency for barrier-drain hiding.
__global__ __launch_bounds__(256, 2) void gemm_f16_kernel(
    const unsigned short* __restrict__ xf, const unsigned short* __restrict__ wf,
    const float* __restrict__ bias, const unsigned char* __restrict__ mask,
    float* __restrict__ out) {
  __shared__ __align__(16) unsigned short smem[2 * 4096];  // A | B panels, 16384 B

  // XCD-aware swizzle (2048 blocks % 8 == 0 -> simple remap is bijective)
  int bid = blockIdx.x;
  int sid = (bid & 7) * 256 + (bid >> 3);
  int bm = sid >> 6;   // 0..31
  int bn = sid & 63;   // 0..63
  int row0 = bm * 128, col0 = bn * 128;

  int t = threadIdx.x, lane = t & 63, w = t >> 6;
  int wrow = (w >> 1) * 64, wcol = (w & 1) * 64;

  // staging geometry: linear LDS byte L = (w*2+i)*1024 + lane*16
  // row = L>>6 (64B rows), slot s = (L>>4)&3; slot s holds global k-group g = s ^ ((row>>1)&3)
  int Lr[2], Lg[2];
#pragma unroll
  for (int i = 0; i < 2; ++i) {
    int L = (w * 2 + i) * 1024 + lane * 16;
    int row = L >> 6;
    int s = (L >> 4) & 3;
    Lr[i] = row;
    Lg[i] = s ^ ((row >> 1) & 3);
  }

  // fragment read offsets (halfwords), constant over kt
  int aoff[4], boff[4];
  int g = lane >> 4;
#pragma unroll
  for (int m = 0; m < 4; ++m) {
    int row = wrow + m * 16 + (lane & 15);
    aoff[m] = row * 32 + ((g ^ ((row >> 1) & 3)) * 8);
  }
#pragma unroll
  for (int n = 0; n < 4; ++n) {
    int row = wcol + n * 16 + (lane & 15);
    boff[n] = row * 32 + ((g ^ ((row >> 1) & 3)) * 8);
  }

  f32x4 acc[4][4];
#pragma unroll
  for (int m = 0; m < 4; ++m)
#pragma unroll
    for (int n = 0; n < 4; ++n) acc[m][n] = (f32x4){0.0f, 0.0f, 0.0f, 0.0f};

  // running staging pointers (strength-reduced: +32 halfwords per K-step)
  const unsigned short* gpa0 = xf + (size_t)(row0 + Lr[0]) * K_DIM + Lg[0] * 8;
  const unsigned short* gpa1 = xf + (size_t)(row0 + Lr[1]) * K_DIM + Lg[1] * 8;
  const unsigned short* gpb0 = wf + (size_t)(col0 + Lr[0]) * K_DIM + Lg[0] * 8;
  const unsigned short* gpb1 = wf + (size_t)(col0 + Lr[1]) * K_DIM + Lg[1] * 8;
  char* lpa0 = (char*)smem + (w * 2 + 0) * 1024;
  char* lpa1 = (char*)smem + (w * 2 + 1) * 1024;
  char* lpb0 = lpa0 + 8192;
  char* lpb1 = lpa1 + 8192;

#pragma unroll 1
  for (int kt = 0; kt < K_DIM / 32; ++kt) {
    gload16(gpa0, lpa0);
    gload16(gpa1, lpa1);
    gload16(gpb0, lpb0);
    gload16(gpb1, lpb1);
    gpa0 += 32; gpa1 += 32; gpb0 += 32; gpb1 += 32;
    __syncthreads();  // compiler drains vmcnt(0) before barrier -> panels ready

    f16x8 a[4], b[4];
#pragma unroll
    for (int m = 0; m < 4; ++m)
      a[m] = *reinterpret_cast<const f16x8*>(&smem[0 * 4096 + aoff[m]]);
#pragma unroll
    for (int n = 0; n < 4; ++n)
      b[n] = *reinterpret_cast<const f16x8*>(&smem[1 * 4096 + boff[n]]);
#pragma unroll
    for (int m = 0; m < 4; ++m)
#pragma unroll
      for (int n = 0; n < 4; ++n)
        acc[m][n] = __builtin_amdgcn_mfma_f32_16x16x32_f16(a[m], b[n], acc[m][n], 0, 0, 0);
    __syncthreads();
  }

  // ---- epilogue: mask-select store (C/D layout: col = lane&15, row = (lane>>4)*4+j) ----
  int cl = lane & 15, rg = lane >> 4;
#pragma unroll
  for (int m = 0; m < 4; ++m) {
    int rb = row0 + wrow + m * 16 + rg * 4;
#pragma unroll
    for (int n = 0; n < 4; ++n) {
      int c = col0 + wcol + n * 16 + cl;
      float bv = bias[c];
#pragma unroll
      for (int j = 0; j < 4; ++j) {
        size_t idx = (size_t)(rb + j) * N_DIM + c;
        out[idx] = mask[idx] ? 0.0f : (acc[m][n][j] + bv);
      }
    }
  }
}

// ---------------- fp32 fallback (only if ws_size too small) ----------------
__device__ __forceinline__ void stats4x4(const float* __restrict__ x,
                                         const float* __restrict__ w,
                                         int r0, int c0,
                                         float (&y1)[4][4], float (&sq)[4][4]) {
#pragma unroll
  for (int i = 0; i < 4; ++i)
#pragma unroll
    for (int j = 0; j < 4; ++j) { y1[i][j] = 0.0f; sq[i][j] = 0.0f; }
#pragma unroll
  for (int kc = 0; kc < 8; ++kc) {
    float4 xa[4], wa[4], x2[4], w2[4];
#pragma unroll
    for (int i = 0; i < 4; ++i)
      xa[i] = *reinterpret_cast<const float4*>(x + (size_t)(r0 + i) * K_DIM + kc * 4);
#pragma unroll
    for (int j = 0; j < 4; ++j)
      wa[j] = *reinterpret_cast<const float4*>(w + (size_t)(c0 + j) * K_DIM + kc * 4);
#pragma unroll
    for (int i = 0; i < 4; ++i)
      x2[i] = make_float4(xa[i].x * xa[i].x, xa[i].y * xa[i].y,
                          xa[i].z * xa[i].z, xa[i].w * xa[i].w);
#pragma unroll
    for (int j = 0; j < 4; ++j)
      w2[j] = make_float4(wa[j].x * wa[j].x, wa[j].y * wa[j].y,
                          wa[j].z * wa[j].z, wa[j].w * wa[j].w);
#pragma unroll
    for (int i = 0; i < 4; ++i)
#pragma unroll
      for (int j = 0; j < 4; ++j) {
        float a = y1[i][j];
        a = fmaf(xa[i].x, wa[j].x, a);
        a = fmaf(xa[i].y, wa[j].y, a);
        a = fmaf(xa[i].z, wa[j].z, a);
        a = fmaf(xa[i].w, wa[j].w, a);
        y1[i][j] = a;
        float b = sq[i][j];
        b = fmaf(x2[i].x, w2[j].x, b);
        b = fmaf(x2[i].y, w2[j].y, b);
        b = fmaf(x2[i].z, w2[j].z, b);
        b = fmaf(x2[i].w, w2[j].w, b);
        sq[i][j] = b;
      }
  }
}

__global__ void fallback_gemm_kernel(const float* __restrict__ x, const float* __restrict__ wgt,
                                     const float* __restrict__ bias, const float* __restrict__ swp,
                                     const float* __restrict__ sbp, float* __restrict__ out) {
  __shared__ float xs[64][36], ws2[64][36];
  int t = threadIdx.x;
  int tr = t >> 4, tc = t & 15;
  int r0 = blockIdx.x * 64, c0 = blockIdx.y * 64;
  float acc[4][4];
#pragma unroll
  for (int i = 0; i < 4; ++i)
#pragma unroll
    for (int j = 0; j < 4; ++j) acc[i][j] = 0.0f;

#pragma unroll 1
  for (int kt = 0; kt < K_DIM / 32; ++kt) {
#pragma unroll
    for (int i = 0; i < 2; ++i) {
      int idx = t + 256 * i;
      int row = idx >> 3;
      int kk = (idx & 7) * 4;
      *reinterpret_cast<float4*>(&xs[row][kk]) =
          *reinterpret_cast<const float4*>(x + (size_t)(r0 + row) * K_DIM + kt * 32 + kk);
      *reinterpret_cast<float4*>(&ws2[row][kk]) =
          *reinterpret_cast<const float4*>(wgt + (size_t)(c0 + row) * K_DIM + kt * 32 + kk);
    }
    __syncthreads();
#pragma unroll 4
    for (int k = 0; k < 32; ++k) {
      float xv[4], wv[4];
#pragma unroll
      for (int i = 0; i < 4; ++i) { xv[i] = xs[tr * 4 + i][k]; wv[i] = ws2[tc * 4 + i][k]; }
#pragma unroll
      for (int i = 0; i < 4; ++i)
#pragma unroll
        for (int j = 0; j < 4; ++j) acc[i][j] = fmaf(xv[i], wv[j], acc[i][j]);
    }
    __syncthreads();
  }

  float y1[4][4], sq[4][4];
  stats4x4(x, wgt, r0 + tr * 4, c0 + tc * 4, y1, sq);
  float sw = *swp, sb = *sbp;
#pragma unroll
  for (int i = 0; i < 4; ++i)
#pragma unroll
    for (int j = 0; j < 4; ++j) {
      int r = r0 + tr * 4 + i, c = c0 + tc * 4 + j;
      float bv = bias[c];
      unsigned char p = gate_passed(y1[i][j] + bv, sq[i][j], sw, sb);
      out[(size_t)r * N_DIM + c] = p ? 0.0f : (acc[i][j] + bv);
    }
}

extern "C" void kernel_launch(void* const* d_in, const int* in_sizes, int n_in,
                              void* d_out, int out_size, void* d_ws, size_t ws_size,
                              hipStream_t stream) {
  (void)in_sizes; (void)n_in; (void)out_size;
  const float* x    = (const float*)d_in[0];
  const float* wgt  = (const float*)d_in[1];
  const float* bias = (const float*)d_in[2];
  const float* swp  = (const float*)d_in[3];
  const float* sbp  = (const float*)d_in[4];
  float* out = (float*)d_out;

  const size_t xf_off = 0;
  const size_t wf_off = xf_off + (size_t)M_DIM * K_DIM * 2;    // 16 MB
  const size_t xe_off = wf_off + (size_t)N_DIM * K_DIM * 2;    // 48 MB
  const size_t we_off = xe_off + (size_t)M_DIM * 32 * 4;       // +512 KB
  const size_t mk_off = we_off + (size_t)N_DIM * 32 * 4;       // +1 MB
  const size_t need   = mk_off + (size_t)M_DIM * N_DIM;        // +32 MB -> 81.5 MB

  if (ws_size >= need) {
    unsigned short* xf = (unsigned short*)((char*)d_ws + xf_off);
    unsigned short* wf = (unsigned short*)((char*)d_ws + wf_off);
    float* xe = (float*)((char*)d_ws + xe_off);
    float* we = (float*)((char*)d_ws + we_off);
    unsigned char* mk  = (unsigned char*)((char*)d_ws + mk_off);

    int n4x = M_DIM * K_DIM / 4;
    int n4tot = n4x + N_DIM * K_DIM / 4;
    hipLaunchKernelGGL(cvt_f16_fused_kernel, dim3(2048), dim3(256), 0, stream,
                       x, wgt, xf, wf, xe, we, n4x, n4tot);
    hipLaunchKernelGGL(mask_kernel, dim3(M_DIM / 128, N_DIM / 128), dim3(256), 0, stream,
                       xe, we, bias, swp, sbp, mk);
    hipLaunchKernelGGL(gemm_f16_kernel, dim3(2048), dim3(256), 0, stream,
                       xf, wf, bias, mk, out);
  } else {
    hipLaunchKernelGGL(fallback_gemm_kernel, dim3(M_DIM / 64, N_DIM / 64), dim3(256), 0, stream,
                       x, wgt, bias, swp, sbp, out);
  }
}

// Round 12
// 309.140 us; speedup vs baseline: 3.5575x; 3.5575x over previous
//
#include <hip/hip_runtime.h>
#include <hip/hip_bf16.h>
#include <hip/hip_fp16.h>
#include <stdint.h>

#define M_DIM 4096   // B*S
#define K_DIM 2048   // H
#define N_DIM 8192   // OUT

typedef __attribute__((ext_vector_type(4))) float f32x4;
typedef __attribute__((ext_vector_type(8))) _Float16 f16x8;

typedef __attribute__((address_space(1))) const unsigned int g_u32_t;
typedef __attribute__((address_space(3))) unsigned int lds_u32_t;

static __device__ __forceinline__ void gload16(const void* g, void* l) {
  // global -> LDS direct copy, 16B per lane; LDS dest = wave-uniform base + lane*16
  __builtin_amdgcn_global_load_lds((g_u32_t*)g, (lds_u32_t*)l, 16, 0, 0);
}

#define BOUNDF ((float)(-2.053748910631823))

__device__ __forceinline__ unsigned char gate_passed(float y1v, float sqv,
                                                     float sw, float sb) {
  // mirrors the reference op-for-op; cm*cm is PINNED so the compiler cannot
  // contract (sqv/32 - cm*cm) into fma(-cm, cm, sqv/32) — knife-edge gate
  // elements flip on that 1-ulp difference (round-8/9 failure mode).
  float cm = y1v / 32.0f * sw + sb;
  float cmsq = cm * cm;
  asm volatile("" : "+v"(cmsq));
  float cv = (sqv / 32.0f - cmsq) * sw * sw;
  float ts = cm / sqrtf(cv / 32.0f);
  return (ts < BOUNDF) ? (unsigned char)1 : (unsigned char)0;
}

// ------- fused convert fp32 -> fp16 (RTN) for BOTH x and w, plus packed E-prefix -------
__global__ void cvt_f16_fused_kernel(const float* __restrict__ x,
                                     const float* __restrict__ wgt,
                                     unsigned short* __restrict__ xf,
                                     unsigned short* __restrict__ wf,
                                     float* __restrict__ xe,
                                     float* __restrict__ we,
                                     int n4x, int n4tot) {
  int i = blockIdx.x * blockDim.x + threadIdx.x;
  int stride = gridDim.x * blockDim.x;
  for (; i < n4tot; i += stride) {
    const float* src;
    unsigned short* dst;
    float* pe;
    int idx;
    if (i < n4x) {
      src = x; dst = xf; pe = xe; idx = i;
    } else {
      src = wgt; dst = wf; pe = we; idx = i - n4x;
    }
    float4 v = reinterpret_cast<const float4*>(src)[idx];
    int col4 = idx & (K_DIM / 4 - 1);
    if (col4 < 8) {
      int row = idx >> 9;  // K_DIM/4 = 512
      reinterpret_cast<float4*>(pe)[row * 8 + col4] = v;
    }
    float xs[4] = {v.x, v.y, v.z, v.w};
    unsigned short hb[4];
#pragma unroll
    for (int j = 0; j < 4; ++j) {
      _Float16 h = (_Float16)xs[j];  // v_cvt_f16_f32, round-to-nearest
      hb[j] = *reinterpret_cast<unsigned short*>(&h);
    }
    reinterpret_cast<ushort4*>(dst)[idx] = make_ushort4(hb[0], hb[1], hb[2], hb[3]);
  }
}

// ---------------- gate mask kernel: exact fp32 E=32 stats -> byte mask ----------------
// k-outer structure: all 16 rows' accumulators live (y1/sq[16][4] = 128 VGPRs),
// wv read ONCE per k: LDS reads 640/thread (vs 1024 m-outer). Per-output fmaf
// chain bit-identical to rounds 3-10 (k ascends for every output; all indices
// compile-time per rule #20).
// ROUND-12 FIX: __launch_bounds__(256,2) -> VGPR cap 256. Round 11 omitted it
// and the DEFAULT cap (64, for 1024-thread workgroups) spilled all 128
// accumulator registers to scratch: 3.1 GB writes, 894 us.
__global__ __launch_bounds__(256, 2) void mask_kernel(
    const float* __restrict__ xe_packed, const float* __restrict__ we_packed,
    const float* __restrict__ bias, const float* __restrict__ swp,
    const float* __restrict__ sbp, unsigned char* __restrict__ mask) {
  __shared__ __align__(16) unsigned char smem_bytes[128 * 36 * 4 + 32 * 128 * 4];
  float* xe_lds = (float*)smem_bytes;                      // [128][36]
  float* we_lds = (float*)(smem_bytes + 128 * 36 * 4);     // [32][128]

  int row0 = blockIdx.x * 128, col0 = blockIdx.y * 128;
  int t = threadIdx.x, lane = t & 63, w = t >> 6;
  int wrow = (w >> 1) * 64, wcol = (w & 1) * 64;
  int cl = lane & 15, rg = lane >> 4;

  // stage x_e tile: 128 rows x 32 f32 = 1024 float4; 4 per thread
#pragma unroll
  for (int it = 0; it < 4; ++it) {
    int idx = it * 256 + t;
    int r = idx >> 3, q = idx & 7;
    float4 v = reinterpret_cast<const float4*>(xe_packed)[(size_t)(row0 + r) * 8 + q];
    *reinterpret_cast<float4*>(&xe_lds[r * 36 + q * 4]) = v;
  }
  // stage w_e tile transposed to k-major: [32][128]
#pragma unroll
  for (int it = 0; it < 4; ++it) {
    int idx = it * 256 + t;
    int c = idx & 127, kq = idx >> 7;  // kq = 0..7
    float4 v = reinterpret_cast<const float4*>(we_packed)[(size_t)(col0 + c) * 8 + kq];
    we_lds[(kq * 4 + 0) * 128 + c] = v.x;
    we_lds[(kq * 4 + 1) * 128 + c] = v.y;
    we_lds[(kq * 4 + 2) * 128 + c] = v.z;
    we_lds[(kq * 4 + 3) * 128 + c] = v.w;
  }
  __syncthreads();

  float sw = *swp, sb = *sbp;

  float y1[16][4], sq[16][4];  // [m*4+j][n]
#pragma unroll
  for (int r = 0; r < 16; ++r)
#pragma unroll
    for (int n = 0; n < 4; ++n) { y1[r][n] = 0.0f; sq[r][n] = 0.0f; }

#pragma unroll 2
  for (int k = 0; k < 32; ++k) {
    float wv[4], wv2[4];
#pragma unroll
    for (int n = 0; n < 4; ++n) {
      wv[n] = we_lds[k * 128 + wcol + n * 16 + cl];
      wv2[n] = wv[n] * wv[n];
    }
#pragma unroll
    for (int m = 0; m < 4; ++m) {
#pragma unroll
      for (int j = 0; j < 4; ++j) {
        float xv = xe_lds[(wrow + m * 16 + rg * 4 + j) * 36 + k];
        float xv2 = xv * xv;
#pragma unroll
        for (int n = 0; n < 4; ++n) {
          y1[m * 4 + j][n] = fmaf(xv, wv[n], y1[m * 4 + j][n]);
          sq[m * 4 + j][n] = fmaf(xv2, wv2[n], sq[m * 4 + j][n]);
        }
      }
    }
  }

#pragma unroll
  for (int m = 0; m < 4; ++m) {
#pragma unroll
    for (int n = 0; n < 4; ++n) {
      int c = col0 + wcol + n * 16 + cl;
      float bv = bias[c];
#pragma unroll
      for (int j = 0; j < 4; ++j) {
        int r = row0 + wrow + m * 16 + rg * 4 + j;
        mask[(size_t)r * N_DIM + c] =
            gate_passed(y1[m * 4 + j][n] + bv, sq[m * 4 + j][n], sw, sb);
      }
    }
  }
}

// ---------------- main GEMM: single fp16 MFMA term, mask-select epilogue ----------------
// m97 structure: 128x128 tile, BK=32, 4 waves, global_load_lds width 16,
// XOR-swizzled 16B LDS slots, 8 ds_read_b128 + 16 MFMA per K-step.
// LDS = 16 KB only (gate moved out) -> high residency for barrier-drain hiding.
__global__ __launch_bounds__(256, 2) void gemm_f16_kernel(
    const unsigned short* __restrict__ xf, const unsigned short* __restrict__ wf,
    const float* __restrict__ bias, const unsigned char* __restrict__ mask,
    float* __restrict__ out) {
  __shared__ __align__(16) unsigned short smem[2 * 4096];  // A | B panels, 16384 B

  // XCD-aware swizzle (2048 blocks % 8 == 0 -> simple remap is bijective)
  int bid = blockIdx.x;
  int sid = (bid & 7) * 256 + (bid >> 3);
  int bm = sid >> 6;   // 0..31
  int bn = sid & 63;   // 0..63
  int row0 = bm * 128, col0 = bn * 128;

  int t = threadIdx.x, lane = t & 63, w = t >> 6;
  int wrow = (w >> 1) * 64, wcol = (w & 1) * 64;

  // staging geometry: linear LDS byte L = (w*2+i)*1024 + lane*16
  // row = L>>6 (64B rows), slot s = (L>>4)&3; slot s holds global k-group g = s ^ ((row>>1)&3)
  int Lr[2], Lg[2];
#pragma unroll
  for (int i = 0; i < 2; ++i) {
    int L = (w * 2 + i) * 1024 + lane * 16;
    int row = L >> 6;
    int s = (L >> 4) & 3;
    Lr[i] = row;
    Lg[i] = s ^ ((row >> 1) & 3);
  }

  // fragment read offsets (halfwords), constant over kt
  int aoff[4], boff[4];
  int g = lane >> 4;
#pragma unroll
  for (int m = 0; m < 4; ++m) {
    int row = wrow + m * 16 + (lane & 15);
    aoff[m] = row * 32 + ((g ^ ((row >> 1) & 3)) * 8);
  }
#pragma unroll
  for (int n = 0; n < 4; ++n) {
    int row = wcol + n * 16 + (lane & 15);
    boff[n] = row * 32 + ((g ^ ((row >> 1) & 3)) * 8);
  }

  f32x4 acc[4][4];
#pragma unroll
  for (int m = 0; m < 4; ++m)
#pragma unroll
    for (int n = 0; n < 4; ++n) acc[m][n] = (f32x4){0.0f, 0.0f, 0.0f, 0.0f};

  // running staging pointers (strength-reduced: +32 halfwords per K-step)
  const unsigned short* gpa0 = xf + (size_t)(row0 + Lr[0]) * K_DIM + Lg[0] * 8;
  const unsigned short* gpa1 = xf + (size_t)(row0 + Lr[1]) * K_DIM + Lg[1] * 8;
  const unsigned short* gpb0 = wf + (size_t)(col0 + Lr[0]) * K_DIM + Lg[0] * 8;
  const unsigned short* gpb1 = wf + (size_t)(col0 + Lr[1]) * K_DIM + Lg[1] * 8;
  char* lpa0 = (char*)smem + (w * 2 + 0) * 1024;
  char* lpa1 = (char*)smem + (w * 2 + 1) * 1024;
  char* lpb0 = lpa0 + 8192;
  char* lpb1 = lpa1 + 8192;

#pragma unroll 1
  for (int kt = 0; kt < K_DIM / 32; ++kt) {
    gload16(gpa0, lpa0);
    gload16(gpa1, lpa1);
    gload16(gpb0, lpb0);
    gload16(gpb1, lpb1);
    gpa0 += 32; gpa1 += 32; gpb0 += 32; gpb1 += 32;
    __syncthreads();  // compiler drains vmcnt(0) before barrier -> panels ready

    f16x8 a[4], b[4];
#pragma unroll
    for (int m = 0; m < 4; ++m)
      a[m] = *reinterpret_cast<const f16x8*>(&smem[0 * 4096 + aoff[m]]);
#pragma unroll
    for (int n = 0; n < 4; ++n)
      b[n] = *reinterpret_cast<const f16x8*>(&smem[1 * 4096 + boff[n]]);
#pragma unroll
    for (int m = 0; m < 4; ++m)
#pragma unroll
      for (int n = 0; n < 4; ++n)
        acc[m][n] = __builtin_amdgcn_mfma_f32_16x16x32_f16(a[m], b[n], acc[m][n], 0, 0, 0);
    __syncthreads();
  }

  // ---- epilogue: mask-select store (C/D layout: col = lane&15, row = (lane>>4)*4+j) ----
  int cl = lane & 15, rg = lane >> 4;
#pragma unroll
  for (int m = 0; m < 4; ++m) {
    int rb = row0 + wrow + m * 16 + rg * 4;
#pragma unroll
    for (int n = 0; n < 4; ++n) {
      int c = col0 + wcol + n * 16 + cl;
      float bv = bias[c];
#pragma unroll
      for (int j = 0; j < 4; ++j) {
        size_t idx = (size_t)(rb + j) * N_DIM + c;
        out[idx] = mask[idx] ? 0.0f : (acc[m][n][j] + bv);
      }
    }
  }
}

// ---------------- fp32 fallback (only if ws_size too small) ----------------
__device__ __forceinline__ void stats4x4(const float* __restrict__ x,
                                         const float* __restrict__ w,
                                         int r0, int c0,
                                         float (&y1)[4][4], float (&sq)[4][4]) {
#pragma unroll
  for (int i = 0; i < 4; ++i)
#pragma unroll
    for (int j = 0; j < 4; ++j) { y1[i][j] = 0.0f; sq[i][j] = 0.0f; }
#pragma unroll
  for (int kc = 0; kc < 8; ++kc) {
    float4 xa[4], wa[4], x2[4], w2[4];
#pragma unroll
    for (int i = 0; i < 4; ++i)
      xa[i] = *reinterpret_cast<const float4*>(x + (size_t)(r0 + i) * K_DIM + kc * 4);
#pragma unroll
    for (int j = 0; j < 4; ++j)
      wa[j] = *reinterpret_cast<const float4*>(w + (size_t)(c0 + j) * K_DIM + kc * 4);
#pragma unroll
    for (int i = 0; i < 4; ++i)
      x2[i] = make_float4(xa[i].x * xa[i].x, xa[i].y * xa[i].y,
                          xa[i].z * xa[i].z, xa[i].w * xa[i].w);
#pragma unroll
    for (int j = 0; j < 4; ++j)
      w2[j] = make_float4(wa[j].x * wa[j].x, wa[j].y * wa[j].y,
                          wa[j].z * wa[j].z, wa[j].w * wa[j].w);
#pragma unroll
    for (int i = 0; i < 4; ++i)
#pragma unroll
      for (int j = 0; j < 4; ++j) {
        float a = y1[i][j];
        a = fmaf(xa[i].x, wa[j].x, a);
        a = fmaf(xa[i].y, wa[j].y, a);
        a = fmaf(xa[i].z, wa[j].z, a);
        a = fmaf(xa[i].w, wa[j].w, a);
        y1[i][j] = a;
        float b = sq[i][j];
        b = fmaf(x2[i].x, w2[j].x, b);
        b = fmaf(x2[i].y, w2[j].y, b);
        b = fmaf(x2[i].z, w2[j].z, b);
        b = fmaf(x2[i].w, w2[j].w, b);
        sq[i][j] = b;
      }
  }
}

__global__ void fallback_gemm_kernel(const float* __restrict__ x, const float* __restrict__ wgt,
                                     const float* __restrict__ bias, const float* __restrict__ swp,
                                     const float* __restrict__ sbp, float* __restrict__ out) {
  __shared__ float xs[64][36], ws2[64][36];
  int t = threadIdx.x;
  int tr = t >> 4, tc = t & 15;
  int r0 = blockIdx.x * 64, c0 = blockIdx.y * 64;
  float acc[4][4];
#pragma unroll
  for (int i = 0; i < 4; ++i)
#pragma unroll
    for (int j = 0; j < 4; ++j) acc[i][j] = 0.0f;

#pragma unroll 1
  for (int kt = 0; kt < K_DIM / 32; ++kt) {
#pragma unroll
    for (int i = 0; i < 2; ++i) {
      int idx = t + 256 * i;
      int row = idx >> 3;
      int kk = (idx & 7) * 4;
      *reinterpret_cast<float4*>(&xs[row][kk]) =
          *reinterpret_cast<const float4*>(x + (size_t)(r0 + row) * K_DIM + kt * 32 + kk);
      *reinterpret_cast<float4*>(&ws2[row][kk]) =
          *reinterpret_cast<const float4*>(wgt + (size_t)(c0 + row) * K_DIM + kt * 32 + kk);
    }
    __syncthreads();
#pragma unroll 4
    for (int k = 0; k < 32; ++k) {
      float xv[4], wv[4];
#pragma unroll
      for (int i = 0; i < 4; ++i) { xv[i] = xs[tr * 4 + i][k]; wv[i] = ws2[tc * 4 + i][k]; }
#pragma unroll
      for (int i = 0; i < 4; ++i)
#pragma unroll
        for (int j = 0; j < 4; ++j) acc[i][j] = fmaf(xv[i], wv[j], acc[i][j]);
    }
    __syncthreads();
  }

  float y1[4][4], sq[4][4];
  stats4x4(x, wgt, r0 + tr * 4, c0 + tc * 4, y1, sq);
  float sw = *swp, sb = *sbp;
#pragma unroll
  for (int i = 0; i < 4; ++i)
#pragma unroll
    for (int j = 0; j < 4; ++j) {
      int r = r0 + tr * 4 + i, c = c0 + tc * 4 + j;
      float bv = bias[c];
      unsigned char p = gate_passed(y1[i][j] + bv, sq[i][j], sw, sb);
      out[(size_t)r * N_DIM + c] = p ? 0.0f : (acc[i][j] + bv);
    }
}

extern "C" void kernel_launch(void* const* d_in, const int* in_sizes, int n_in,
                              void* d_out, int out_size, void* d_ws, size_t ws_size,
                              hipStream_t stream) {
  (void)in_sizes; (void)n_in; (void)out_size;
  const float* x    = (const float*)d_in[0];
  const float* wgt  = (const float*)d_in[1];
  const float* bias = (const float*)d_in[2];
  const float* swp  = (const float*)d_in[3];
  const float* sbp  = (const float*)d_in[4];
  float* out = (float*)d_out;

  const size_t xf_off = 0;
  const size_t wf_off = xf_off + (size_t)M_DIM * K_DIM * 2;    // 16 MB
  const size_t xe_off = wf_off + (size_t)N_DIM * K_DIM * 2;    // 48 MB
  const size_t we_off = xe_off + (size_t)M_DIM * 32 * 4;       // +512 KB
  const size_t mk_off = we_off + (size_t)N_DIM * 32 * 4;       // +1 MB
  const size_t need   = mk_off + (size_t)M_DIM * N_DIM;        // +32 MB -> 81.5 MB

  if (ws_size >= need) {
    unsigned short* xf = (unsigned short*)((char*)d_ws + xf_off);
    unsigned short* wf = (unsigned short*)((char*)d_ws + wf_off);
    float* xe = (float*)((char*)d_ws + xe_off);
    float* we = (float*)((char*)d_ws + we_off);
    unsigned char* mk  = (unsigned char*)((char*)d_ws + mk_off);

    int n4x = M_DIM * K_DIM / 4;
    int n4tot = n4x + N_DIM * K_DIM / 4;
    hipLaunchKernelGGL(cvt_f16_fused_kernel, dim3(2048), dim3(256), 0, stream,
                       x, wgt, xf, wf, xe, we, n4x, n4tot);
    hipLaunchKernelGGL(mask_kernel, dim3(M_DIM / 128, N_DIM / 128), dim3(256), 0, stream,
                       xe, we, bias, swp, sbp, mk);
    hipLaunchKernelGGL(gemm_f16_kernel, dim3(2048), dim3(256), 0, stream,
                       xf, wf, bias, mk, out);
  } else {
    hipLaunchKernelGGL(fallback_gemm_kernel, dim3(M_DIM / 64, N_DIM / 64), dim3(256), 0, stream,
                       x, wgt, bias, swp, sbp, out);
  }
}

// Round 13
// 299.981 us; speedup vs baseline: 3.6661x; 1.0305x over previous
//
#include <hip/hip_runtime.h>
#include <hip/hip_bf16.h>
#include <hip/hip_fp16.h>
#include <stdint.h>

#define M_DIM 4096   // B*S
#define K_DIM 2048   // H
#define N_DIM 8192   // OUT

typedef __attribute__((ext_vector_type(4))) float f32x4;
typedef __attribute__((ext_vector_type(8))) _Float16 f16x8;

typedef __attribute__((address_space(1))) const unsigned int g_u32_t;
typedef __attribute__((address_space(3))) unsigned int lds_u32_t;

static __device__ __forceinline__ void gload16(const void* g, void* l) {
  // global -> LDS direct copy, 16B per lane; LDS dest = wave-uniform base + lane*16
  __builtin_amdgcn_global_load_lds((g_u32_t*)g, (lds_u32_t*)l, 16, 0, 0);
}

#define BOUNDF ((float)(-2.053748910631823))

__device__ __forceinline__ unsigned char gate_passed(float y1v, float sqv,
                                                     float sw, float sb) {
  // mirrors the reference op-for-op; cm*cm is PINNED so the compiler cannot
  // contract (sqv/32 - cm*cm) into fma(-cm, cm, sqv/32) — knife-edge gate
  // elements flip on that 1-ulp difference (round-8/9 failure mode).
  float cm = y1v / 32.0f * sw + sb;
  float cmsq = cm * cm;
  asm volatile("" : "+v"(cmsq));
  float cv = (sqv / 32.0f - cmsq) * sw * sw;
  float ts = cm / sqrtf(cv / 32.0f);
  return (ts < BOUNDF) ? (unsigned char)1 : (unsigned char)0;
}

// ------- fused convert fp32 -> fp16 (RTN) for BOTH x and w, plus packed E-prefix -------
__global__ void cvt_f16_fused_kernel(const float* __restrict__ x,
                                     const float* __restrict__ wgt,
                                     unsigned short* __restrict__ xf,
                                     unsigned short* __restrict__ wf,
                                     float* __restrict__ xe,
                                     float* __restrict__ we,
                                     int n4x, int n4tot) {
  int i = blockIdx.x * blockDim.x + threadIdx.x;
  int stride = gridDim.x * blockDim.x;
  for (; i < n4tot; i += stride) {
    const float* src;
    unsigned short* dst;
    float* pe;
    int idx;
    if (i < n4x) {
      src = x; dst = xf; pe = xe; idx = i;
    } else {
      src = wgt; dst = wf; pe = we; idx = i - n4x;
    }
    float4 v = reinterpret_cast<const float4*>(src)[idx];
    int col4 = idx & (K_DIM / 4 - 1);
    if (col4 < 8) {
      int row = idx >> 9;  // K_DIM/4 = 512
      reinterpret_cast<float4*>(pe)[row * 8 + col4] = v;
    }
    float xs[4] = {v.x, v.y, v.z, v.w};
    unsigned short hb[4];
#pragma unroll
    for (int j = 0; j < 4; ++j) {
      _Float16 h = (_Float16)xs[j];  // v_cvt_f16_f32, round-to-nearest
      hb[j] = *reinterpret_cast<unsigned short*>(&h);
    }
    reinterpret_cast<ushort4*>(dst)[idx] = make_ushort4(hb[0], hb[1], hb[2], hb[3]);
  }
}

// ---------------- gate mask kernel: exact fp32 E=32 stats -> byte mask ----------------
// Round-13: b128 LDS reads. Both E-tiles stored [128][36] row-major; per (row,kq)
// one f32x4 read -> LDS instrs 640 -> 160 per thread (the round-12 counter math
// showed ~50us of LDS-pipe time in scalar b32 form). Per-output fmaf chain is
// BIT-IDENTICAL to round 12: kq-outer/kk-inner = k ascending 0..31; wvsq is the
// same rounded wv*wv; fmaf args unchanged.
// k-outer accumulators y1/sq[16][4] (128 VGPRs) + __launch_bounds__(256,2)
// (VGPR cap 256 — round-11's missing-bounds default cap of 64 spilled it all).
__global__ __launch_bounds__(256, 2) void mask_kernel(
    const float* __restrict__ xe_packed, const float* __restrict__ we_packed,
    const float* __restrict__ bias, const float* __restrict__ swp,
    const float* __restrict__ sbp, unsigned char* __restrict__ mask) {
  __shared__ __align__(16) unsigned char smem_bytes[2 * 128 * 36 * 4];
  float* xe_lds = (float*)smem_bytes;                      // [128][36]
  float* we_lds = (float*)(smem_bytes + 128 * 36 * 4);     // [128][36]

  int row0 = blockIdx.x * 128, col0 = blockIdx.y * 128;
  int t = threadIdx.x, lane = t & 63, w = t >> 6;
  int wrow = (w >> 1) * 64, wcol = (w & 1) * 64;
  int cl = lane & 15, rg = lane >> 4;

  // stage both tiles: 128 rows x 32 f32 = 1024 float4 each; 4 per thread each
#pragma unroll
  for (int it = 0; it < 4; ++it) {
    int idx = it * 256 + t;
    int r = idx >> 3, q = idx & 7;
    *reinterpret_cast<float4*>(&xe_lds[r * 36 + q * 4]) =
        reinterpret_cast<const float4*>(xe_packed)[(size_t)(row0 + r) * 8 + q];
    *reinterpret_cast<float4*>(&we_lds[r * 36 + q * 4]) =
        reinterpret_cast<const float4*>(we_packed)[(size_t)(col0 + r) * 8 + q];
  }
  __syncthreads();

  float sw = *swp, sb = *sbp;

  float y1[16][4], sq[16][4];  // [m*4+j][n]
#pragma unroll
  for (int r = 0; r < 16; ++r)
#pragma unroll
    for (int n = 0; n < 4; ++n) { y1[r][n] = 0.0f; sq[r][n] = 0.0f; }

#pragma unroll
  for (int kq = 0; kq < 8; ++kq) {
    f32x4 wv4[4], wvsq[4];
#pragma unroll
    for (int n = 0; n < 4; ++n) {
      wv4[n] = *reinterpret_cast<const f32x4*>(&we_lds[(wcol + n * 16 + cl) * 36 + kq * 4]);
      wvsq[n] = wv4[n] * wv4[n];
    }
#pragma unroll
    for (int m = 0; m < 4; ++m) {
#pragma unroll
      for (int j = 0; j < 4; ++j) {
        f32x4 xv4 = *reinterpret_cast<const f32x4*>(
            &xe_lds[(wrow + m * 16 + rg * 4 + j) * 36 + kq * 4]);
#pragma unroll
        for (int kk = 0; kk < 4; ++kk) {
          float xv = xv4[kk];
          float xv2 = xv * xv;
#pragma unroll
          for (int n = 0; n < 4; ++n) {
            y1[m * 4 + j][n] = fmaf(xv, wv4[n][kk], y1[m * 4 + j][n]);
            sq[m * 4 + j][n] = fmaf(xv2, wvsq[n][kk], sq[m * 4 + j][n]);
          }
        }
      }
    }
  }

#pragma unroll
  for (int m = 0; m < 4; ++m) {
#pragma unroll
    for (int n = 0; n < 4; ++n) {
      int c = col0 + wcol + n * 16 + cl;
      float bv = bias[c];
#pragma unroll
      for (int j = 0; j < 4; ++j) {
        int r = row0 + wrow + m * 16 + rg * 4 + j;
        mask[(size_t)r * N_DIM + c] =
            gate_passed(y1[m * 4 + j][n] + bv, sq[m * 4 + j][n], sw, sb);
      }
    }
  }
}

// ---------------- main GEMM: single fp16 MFMA term, mask-select epilogue ----------------
// m97 structure: 128x128 tile, BK=32, 4 waves, global_load_lds width 16,
// XOR-swizzled 16B LDS slots, 8 ds_read_b128 + 16 MFMA per K-step.
// Round-13: SQUARE per-XCD regions (16 bm x 16 bn). The old bm-band mapping gave
// each XCD a 2MB A + 32MB B concurrent footprint (the whole 2048-block grid is
// co-resident at 8 blocks/CU) -> L2 thrash, FETCH 472MB. Square = 8MB + 8MB.
__global__ __launch_bounds__(256, 2) void gemm_f16_kernel(
    const unsigned short* __restrict__ xf, const unsigned short* __restrict__ wf,
    const float* __restrict__ bias, const unsigned char* __restrict__ mask,
    float* __restrict__ out) {
  __shared__ __align__(16) unsigned short smem[2 * 4096];  // A | B panels, 16384 B

  // XCD k = bid&7 (round-robin dispatch); j = bid>>3 sweeps the XCD's 16x16 region
  int bid = blockIdx.x;
  int xk = bid & 7, j = bid >> 3;
  int bm = (xk & 1) * 16 + (j >> 4);   // 0..31
  int bn = (xk >> 1) * 16 + (j & 15);  // 0..63
  int row0 = bm * 128, col0 = bn * 128;

  int t = threadIdx.x, lane = t & 63, w = t >> 6;
  int wrow = (w >> 1) * 64, wcol = (w & 1) * 64;

  // staging geometry: linear LDS byte L = (w*2+i)*1024 + lane*16
  // row = L>>6 (64B rows), slot s = (L>>4)&3; slot s holds global k-group g = s ^ ((row>>1)&3)
  int Lr[2], Lg[2];
#pragma unroll
  for (int i = 0; i < 2; ++i) {
    int L = (w * 2 + i) * 1024 + lane * 16;
    int row = L >> 6;
    int s = (L >> 4) & 3;
    Lr[i] = row;
    Lg[i] = s ^ ((row >> 1) & 3);
  }

  // fragment read offsets (halfwords), constant over kt
  int aoff[4], boff[4];
  int g = lane >> 4;
#pragma unroll
  for (int m = 0; m < 4; ++m) {
    int row = wrow + m * 16 + (lane & 15);
    aoff[m] = row * 32 + ((g ^ ((row >> 1) & 3)) * 8);
  }
#pragma unroll
  for (int n = 0; n < 4; ++n) {
    int row = wcol + n * 16 + (lane & 15);
    boff[n] = row * 32 + ((g ^ ((row >> 1) & 3)) * 8);
  }

  f32x4 acc[4][4];
#pragma unroll
  for (int m = 0; m < 4; ++m)
#pragma unroll
    for (int n = 0; n < 4; ++n) acc[m][n] = (f32x4){0.0f, 0.0f, 0.0f, 0.0f};

  // running staging pointers (strength-reduced: +32 halfwords per K-step)
  const unsigned short* gpa0 = xf + (size_t)(row0 + Lr[0]) * K_DIM + Lg[0] * 8;
  const unsigned short* gpa1 = xf + (size_t)(row0 + Lr[1]) * K_DIM + Lg[1] * 8;
  const unsigned short* gpb0 = wf + (size_t)(col0 + Lr[0]) * K_DIM + Lg[0] * 8;
  const unsigned short* gpb1 = wf + (size_t)(col0 + Lr[1]) * K_DIM + Lg[1] * 8;
  char* lpa0 = (char*)smem + (w * 2 + 0) * 1024;
  char* lpa1 = (char*)smem + (w * 2 + 1) * 1024;
  char* lpb0 = lpa0 + 8192;
  char* lpb1 = lpa1 + 8192;

#pragma unroll 1
  for (int kt = 0; kt < K_DIM / 32; ++kt) {
    gload16(gpa0, lpa0);
    gload16(gpa1, lpa1);
    gload16(gpb0, lpb0);
    gload16(gpb1, lpb1);
    gpa0 += 32; gpa1 += 32; gpb0 += 32; gpb1 += 32;
    __syncthreads();  // compiler drains vmcnt(0) before barrier -> panels ready

    f16x8 a[4], b[4];
#pragma unroll
    for (int m = 0; m < 4; ++m)
      a[m] = *reinterpret_cast<const f16x8*>(&smem[0 * 4096 + aoff[m]]);
#pragma unroll
    for (int n = 0; n < 4; ++n)
      b[n] = *reinterpret_cast<const f16x8*>(&smem[1 * 4096 + boff[n]]);
#pragma unroll
    for (int m = 0; m < 4; ++m)
#pragma unroll
      for (int n = 0; n < 4; ++n)
        acc[m][n] = __builtin_amdgcn_mfma_f32_16x16x32_f16(a[m], b[n], acc[m][n], 0, 0, 0);
    __syncthreads();
  }

  // ---- epilogue: mask-select store (C/D layout: col = lane&15, row = (lane>>4)*4+j) ----
  int cl = lane & 15, rg = lane >> 4;
#pragma unroll
  for (int m = 0; m < 4; ++m) {
    int rb = row0 + wrow + m * 16 + rg * 4;
#pragma unroll
    for (int n = 0; n < 4; ++n) {
      int c = col0 + wcol + n * 16 + cl;
      float bv = bias[c];
#pragma unroll
      for (int j = 0; j < 4; ++j) {
        size_t idx = (size_t)(rb + j) * N_DIM + c;
        out[idx] = mask[idx] ? 0.0f : (acc[m][n][j] + bv);
      }
    }
  }
}

// ---------------- fp32 fallback (only if ws_size too small) ----------------
__device__ __forceinline__ void stats4x4(const float* __restrict__ x,
                                         const float* __restrict__ w,
                                         int r0, int c0,
                                         float (&y1)[4][4], float (&sq)[4][4]) {
#pragma unroll
  for (int i = 0; i < 4; ++i)
#pragma unroll
    for (int j = 0; j < 4; ++j) { y1[i][j] = 0.0f; sq[i][j] = 0.0f; }
#pragma unroll
  for (int kc = 0; kc < 8; ++kc) {
    float4 xa[4], wa[4], x2[4], w2[4];
#pragma unroll
    for (int i = 0; i < 4; ++i)
      xa[i] = *reinterpret_cast<const float4*>(x + (size_t)(r0 + i) * K_DIM + kc * 4);
#pragma unroll
    for (int j = 0; j < 4; ++j)
      wa[j] = *reinterpret_cast<const float4*>(w + (size_t)(c0 + j) * K_DIM + kc * 4);
#pragma unroll
    for (int i = 0; i < 4; ++i)
      x2[i] = make_float4(xa[i].x * xa[i].x, xa[i].y * xa[i].y,
                          xa[i].z * xa[i].z, xa[i].w * xa[i].w);
#pragma unroll
    for (int j = 0; j < 4; ++j)
      w2[j] = make_float4(wa[j].x * wa[j].x, wa[j].y * wa[j].y,
                          wa[j].z * wa[j].z, wa[j].w * wa[j].w);
#pragma unroll
    for (int i = 0; i < 4; ++i)
#pragma unroll
      for (int j = 0; j < 4; ++j) {
        float a = y1[i][j];
        a = fmaf(xa[i].x, wa[j].x, a);
        a = fmaf(xa[i].y, wa[j].y, a);
        a = fmaf(xa[i].z, wa[j].z, a);
        a = fmaf(xa[i].w, wa[j].w, a);
        y1[i][j] = a;
        float b = sq[i][j];
        b = fmaf(x2[i].x, w2[j].x, b);
        b = fmaf(x2[i].y, w2[j].y, b);
        b = fmaf(x2[i].z, w2[j].z, b);
        b = fmaf(x2[i].w, w2[j].w, b);
        sq[i][j] = b;
      }
  }
}

__global__ void fallback_gemm_kernel(const float* __restrict__ x, const float* __restrict__ wgt,
                                     const float* __restrict__ bias, const float* __restrict__ swp,
                                     const float* __restrict__ sbp, float* __restrict__ out) {
  __shared__ float xs[64][36], ws2[64][36];
  int t = threadIdx.x;
  int tr = t >> 4, tc = t & 15;
  int r0 = blockIdx.x * 64, c0 = blockIdx.y * 64;
  float acc[4][4];
#pragma unroll
  for (int i = 0; i < 4; ++i)
#pragma unroll
    for (int j = 0; j < 4; ++j) acc[i][j] = 0.0f;

#pragma unroll 1
  for (int kt = 0; kt < K_DIM / 32; ++kt) {
#pragma unroll
    for (int i = 0; i < 2; ++i) {
      int idx = t + 256 * i;
      int row = idx >> 3;
      int kk = (idx & 7) * 4;
      *reinterpret_cast<float4*>(&xs[row][kk]) =
          *reinterpret_cast<const float4*>(x + (size_t)(r0 + row) * K_DIM + kt * 32 + kk);
      *reinterpret_cast<float4*>(&ws2[row][kk]) =
          *reinterpret_cast<const float4*>(wgt + (size_t)(c0 + row) * K_DIM + kt * 32 + kk);
    }
    __syncthreads();
#pragma unroll 4
    for (int k = 0; k < 32; ++k) {
      float xv[4], wv[4];
#pragma unroll
      for (int i = 0; i < 4; ++i) { xv[i] = xs[tr * 4 + i][k]; wv[i] = ws2[tc * 4 + i][k]; }
#pragma unroll
      for (int i = 0; i < 4; ++i)
#pragma unroll
        for (int j = 0; j < 4; ++j) acc[i][j] = fmaf(xv[i], wv[j], acc[i][j]);
    }
    __syncthreads();
  }

  float y1[4][4], sq[4][4];
  stats4x4(x, wgt, r0 + tr * 4, c0 + tc * 4, y1, sq);
  float sw = *swp, sb = *sbp;
#pragma unroll
  for (int i = 0; i < 4; ++i)
#pragma unroll
    for (int j = 0; j < 4; ++j) {
      int r = r0 + tr * 4 + i, c = c0 + tc * 4 + j;
      float bv = bias[c];
      unsigned char p = gate_passed(y1[i][j] + bv, sq[i][j], sw, sb);
      out[(size_t)r * N_DIM + c] = p ? 0.0f : (acc[i][j] + bv);
    }
}

extern "C" void kernel_launch(void* const* d_in, const int* in_sizes, int n_in,
                              void* d_out, int out_size, void* d_ws, size_t ws_size,
                              hipStream_t stream) {
  (void)in_sizes; (void)n_in; (void)out_size;
  const float* x    = (const float*)d_in[0];
  const float* wgt  = (const float*)d_in[1];
  const float* bias = (const float*)d_in[2];
  const float* swp  = (const float*)d_in[3];
  const float* sbp  = (const float*)d_in[4];
  float* out = (float*)d_out;

  const size_t xf_off = 0;
  const size_t wf_off = xf_off + (size_t)M_DIM * K_DIM * 2;    // 16 MB
  const size_t xe_off = wf_off + (size_t)N_DIM * K_DIM * 2;    // 48 MB
  const size_t we_off = xe_off + (size_t)M_DIM * 32 * 4;       // +512 KB
  const size_t mk_off = we_off + (size_t)N_DIM * 32 * 4;       // +1 MB
  const size_t need   = mk_off + (size_t)M_DIM * N_DIM;        // +32 MB -> 81.5 MB

  if (ws_size >= need) {
    unsigned short* xf = (unsigned short*)((char*)d_ws + xf_off);
    unsigned short* wf = (unsigned short*)((char*)d_ws + wf_off);
    float* xe = (float*)((char*)d_ws + xe_off);
    float* we = (float*)((char*)d_ws + we_off);
    unsigned char* mk  = (unsigned char*)((char*)d_ws + mk_off);

    int n4x = M_DIM * K_DIM / 4;
    int n4tot = n4x + N_DIM * K_DIM / 4;
    hipLaunchKernelGGL(cvt_f16_fused_kernel, dim3(2048), dim3(256), 0, stream,
                       x, wgt, xf, wf, xe, we, n4x, n4tot);
    hipLaunchKernelGGL(mask_kernel, dim3(M_DIM / 128, N_DIM / 128), dim3(256), 0, stream,
                       xe, we, bias, swp, sbp, mk);
    hipLaunchKernelGGL(gemm_f16_kernel, dim3(2048), dim3(256), 0, stream,
                       xf, wf, bias, mk, out);
  } else {
    hipLaunchKernelGGL(fallback_gemm_kernel, dim3(M_DIM / 64, N_DIM / 64), dim3(256), 0, stream,
                       x, wgt, bias, swp, sbp, out);
  }
}